// Round 2
// baseline (5568.239 us; speedup 1.0000x reference)
//
#include <hip/hip_runtime.h>
#include <hip/hip_bf16.h>

#define N_NODES 100000
#define N_EDGES 600000
#define HDIM 128
#define NLAYERS 4
#define NGRAPH 512
#define NOPS_T 8
#define EPS_MSG 1e-7f
#define EPS_LN 1e-5f

typedef unsigned short u16;
typedef unsigned int u32;

__device__ __forceinline__ float bf2f(u16 u) {
    union { float f; u32 i; } v; v.i = ((u32)u) << 16; return v.f;
}
__device__ __forceinline__ u16 f2bf(float f) {
    union { float f; u32 i; } v; v.f = f;
    u32 r = (v.i + 0x7fffu + ((v.i >> 16) & 1u)) >> 16;   // RNE
    return (u16)r;
}
__device__ __forceinline__ float wave_sum(float v) {
    #pragma unroll
    for (int off = 32; off > 0; off >>= 1) v += __shfl_xor(v, off, 64);
    return v;
}

// ---------------- encoder: h = x @ We + be  (fp32 in/out) ----------------
__global__ __launch_bounds__(256) void k_enc(const float* __restrict__ x,
                                             const float* __restrict__ We,
                                             const float* __restrict__ be,
                                             float* __restrict__ h, int nodes) {
    __shared__ u16 sW[128 * 128];     // bf16 weights, 32 KB
    __shared__ float sx[2][128];
    for (int i = threadIdx.x; i < 128 * 128; i += 256) sW[i] = f2bf(We[i]);
    int sub = threadIdx.x >> 7;       // node within pair
    int col = threadIdx.x & 127;
    float bias = be[col];
    for (int n0 = blockIdx.x * 2; n0 < nodes; n0 += gridDim.x * 2) {
        int n = n0 + sub;
        bool act = n < nodes;
        __syncthreads();
        if (act) sx[sub][col] = x[(size_t)n * 128 + col];
        __syncthreads();
        if (act) {
            float acc = bias;
            const float* xr = sx[sub];
            #pragma unroll 8
            for (int k = 0; k < 128; k++) acc += xr[k] * bf2f(sW[k * 128 + col]);
            h[(size_t)n * 128 + col] = acc;
        }
    }
}

// ------- pre: h2 = bf16(relu(LN(h))) (or plain bf16 copy, layer 0); zero agg -------
__global__ __launch_bounds__(256) void k_pre(const float* __restrict__ h,
                                             const float* __restrict__ gn,
                                             const float* __restrict__ bn,
                                             u16* __restrict__ h2,
                                             float* __restrict__ agg,
                                             int nodes, int do_ln) {
    int wid = threadIdx.x >> 6, lane = threadIdx.x & 63;
    for (int n = blockIdx.x * 4 + wid; n < nodes; n += gridDim.x * 4) {
        size_t base = (size_t)n * 128;
        float a = h[base + lane];
        float b = h[base + 64 + lane];
        float o0, o1;
        if (do_ln) {
            float m = wave_sum(a + b) * (1.f / 128.f);
            float da = a - m, db = b - m;
            float v = wave_sum(da * da + db * db) * (1.f / 128.f);
            float r = rsqrtf(v + EPS_LN);
            o0 = fmaxf(gn[lane] * da * r + bn[lane], 0.f);
            o1 = fmaxf(gn[64 + lane] * db * r + bn[64 + lane], 0.f);
        } else { o0 = a; o1 = b; }
        h2[base + lane] = f2bf(o0);
        h2[base + 64 + lane] = f2bf(o1);
        agg[base + lane] = 0.f;
        agg[base + 64 + lane] = 0.f;
    }
}

// ------- edges: agg[dst] += relu(h2[src] + Etab[attr]) + eps -------
__global__ __launch_bounds__(256) void k_edge(const int* __restrict__ eidx,
                                              const int* __restrict__ eattr,
                                              const float* __restrict__ Etab,
                                              const u16* __restrict__ h2,
                                              float* __restrict__ agg, int nedges) {
    __shared__ float sE[NOPS_T * 128];
    for (int i = threadIdx.x; i < NOPS_T * 128; i += 256) sE[i] = Etab[i];
    __syncthreads();
    int e = blockIdx.x * 2 + (threadIdx.x >> 7);
    int d = threadIdx.x & 127;
    if (e >= nedges) return;
    int s = eidx[e];
    int t = eidx[nedges + e];
    int a = eattr[e];
    float m = bf2f(h2[(size_t)s * 128 + d]) + sE[a * 128 + d];
    m = fmaxf(m, 0.f) + EPS_MSG;
    unsafeAtomicAdd(&agg[(size_t)t * 128 + d], m);
}

// ------- y = bf16(relu(LN((h2 + agg) @ W1 + b1))) -------
__global__ __launch_bounds__(256) void k_y(const u16* __restrict__ h2,
                                           const float* __restrict__ agg,
                                           const float* __restrict__ W1,
                                           const float* __restrict__ b1,
                                           const float* __restrict__ g1,
                                           const float* __restrict__ bb1,
                                           u16* __restrict__ y, int nodes) {
    __shared__ u16 sW[128 * 256];     // bf16 weights, 64 KB
    __shared__ float sin_[128];
    __shared__ float sred[8];
    for (int i = threadIdx.x; i < 128 * 256; i += 256) sW[i] = f2bf(W1[i]);
    int j = threadIdx.x;
    int wid = j >> 6, lane = j & 63;
    float bias = b1[j];
    float gam  = g1[j];
    float bet  = bb1[j];
    for (int n = blockIdx.x; n < nodes; n += gridDim.x) {
        __syncthreads();   // covers weight staging (first iter) + sin_/sred reuse
        if (j < 128) sin_[j] = bf2f(h2[(size_t)n * 128 + j]) + agg[(size_t)n * 128 + j];
        __syncthreads();
        float acc = bias;
        #pragma unroll 8
        for (int k = 0; k < 128; k++) acc += sin_[k] * bf2f(sW[k * 256 + j]);
        // LayerNorm over 256 values (one per thread)
        float s = wave_sum(acc);
        if (lane == 0) sred[wid] = s;
        __syncthreads();
        float mean = (sred[0] + sred[1] + sred[2] + sred[3]) * (1.f / 256.f);
        float d = acc - mean;
        float vs = wave_sum(d * d);
        if (lane == 0) sred[4 + wid] = vs;
        __syncthreads();
        float var = (sred[4] + sred[5] + sred[6] + sred[7]) * (1.f / 256.f);
        float o = fmaxf(gam * d * rsqrtf(var + EPS_LN) + bet, 0.f);
        y[(size_t)n * 256 + j] = f2bf(o);
    }
}

// ------- h = y @ W2 + b2 (+ h if resid) -------
__global__ __launch_bounds__(256) void k_out(const u16* __restrict__ y,
                                             const float* __restrict__ W2,
                                             const float* __restrict__ b2,
                                             float* __restrict__ h, int nodes, int resid) {
    __shared__ u16 sW[256 * 128];     // bf16 weights, 64 KB
    __shared__ float sy[2][256];
    for (int i = threadIdx.x; i < 256 * 128; i += 256) sW[i] = f2bf(W2[i]);
    int sub = threadIdx.x >> 7, col = threadIdx.x & 127;
    float bias = b2[col];
    for (int n0 = blockIdx.x * 2; n0 < nodes; n0 += gridDim.x * 2) {
        int n = n0 + sub;
        bool act = n < nodes;
        __syncthreads();
        if (act) {
            sy[sub][col]       = bf2f(y[(size_t)n * 256 + col]);
            sy[sub][128 + col] = bf2f(y[(size_t)n * 256 + 128 + col]);
        }
        __syncthreads();
        if (act) {
            float acc = bias;
            const float* yr = sy[sub];
            #pragma unroll 8
            for (int k = 0; k < 256; k++) acc += yr[k] * bf2f(sW[k * 128 + col]);
            size_t idx = (size_t)n * 128 + col;
            float prev = resid ? h[idx] : 0.f;
            h[idx] = acc + prev;
        }
    }
}

// ------- final LN + segment-sum pool -------
__global__ __launch_bounds__(256) void k_pool(const float* __restrict__ h,
                                              const float* __restrict__ gn,
                                              const float* __restrict__ bn,
                                              const int* __restrict__ batch,
                                              float* __restrict__ pool,
                                              float* __restrict__ cnt, int nodes) {
    int wid = threadIdx.x >> 6, lane = threadIdx.x & 63;
    for (int n = blockIdx.x * 4 + wid; n < nodes; n += gridDim.x * 4) {
        size_t base = (size_t)n * 128;
        float a = h[base + lane];
        float b = h[base + 64 + lane];
        float m = wave_sum(a + b) * (1.f / 128.f);
        float da = a - m, db = b - m;
        float v = wave_sum(da * da + db * db) * (1.f / 128.f);
        float r = rsqrtf(v + EPS_LN);
        float o0 = gn[lane] * da * r + bn[lane];
        float o1 = gn[64 + lane] * db * r + bn[64 + lane];
        int g = batch[n];
        unsafeAtomicAdd(&pool[(size_t)g * 128 + lane], o0);
        unsafeAtomicAdd(&pool[(size_t)g * 128 + 64 + lane], o1);
        if (lane == 0) unsafeAtomicAdd(&cnt[g], 1.f);
    }
}

// ------- readout: sigmoid(mean_pool @ Wp + bp), fp32 out -------
__global__ __launch_bounds__(64) void k_read(const float* __restrict__ pool,
                                             const float* __restrict__ cnt,
                                             const float* __restrict__ Wp,
                                             const float* __restrict__ bp,
                                             float* __restrict__ out) {
    int g = blockIdx.x, lane = threadIdx.x;
    float inv = 1.f / fmaxf(cnt[g], 1.f);
    float d = (pool[(size_t)g * 128 + lane] * Wp[lane] +
               pool[(size_t)g * 128 + 64 + lane] * Wp[64 + lane]) * inv;
    float s = wave_sum(d);
    if (lane == 0) {
        float z = s + bp[0];
        out[g] = 1.f / (1.f + expf(-z));
    }
}

extern "C" void kernel_launch(void* const* d_in, const int* in_sizes, int n_in,
                              void* d_out, int out_size, void* d_ws, size_t ws_size,
                              hipStream_t stream) {
    const float* x   = (const float*)d_in[0];
    const int*   ei  = (const int*)d_in[1];
    const int*   ea  = (const int*)d_in[2];
    const int*   bat = (const int*)d_in[3];
    const float* We  = (const float*)d_in[4];
    const float* be  = (const float*)d_in[5];
    const float* Et  = (const float*)d_in[6];
    const float* W1  = (const float*)d_in[7];
    const float* b1  = (const float*)d_in[8];
    const float* g1  = (const float*)d_in[9];
    const float* bb1 = (const float*)d_in[10];
    const float* W2  = (const float*)d_in[11];
    const float* b2  = (const float*)d_in[12];
    const float* gn  = (const float*)d_in[13];
    const float* bn  = (const float*)d_in[14];
    const float* Wp  = (const float*)d_in[15];
    const float* bp  = (const float*)d_in[16];
    float* out = (float*)d_out;

    char* w = (char*)d_ws;
    float* h    = (float*)w;  w += (size_t)N_NODES * 128 * 4;
    float* agg  = (float*)w;  w += (size_t)N_NODES * 128 * 4;
    u16*   h2   = (u16*)w;    w += (size_t)N_NODES * 128 * 2;
    u16*   yb   = (u16*)w;    w += (size_t)N_NODES * 256 * 2;
    float* pool = (float*)w;  w += (size_t)NGRAPH * 128 * 4;
    float* cnt  = (float*)w;  w += (size_t)NGRAPH * 4;

    k_enc<<<1024, 256, 0, stream>>>(x, We, be, h, N_NODES);
    for (int l = 0; l < NLAYERS; l++) {
        k_pre<<<1024, 256, 0, stream>>>(h, gn + (l > 0 ? (l - 1) * 128 : 0),
                                        bn + (l > 0 ? (l - 1) * 128 : 0),
                                        h2, agg, N_NODES, l > 0 ? 1 : 0);
        k_edge<<<(N_EDGES + 1) / 2, 256, 0, stream>>>(ei, ea, Et, h2, agg, N_EDGES);
        k_y<<<512, 256, 0, stream>>>(h2, agg, W1 + (size_t)l * 128 * 256,
                                     b1 + l * 256, g1 + l * 256, bb1 + l * 256,
                                     yb, N_NODES);
        k_out<<<512, 256, 0, stream>>>(yb, W2 + (size_t)l * 256 * 128,
                                       b2 + l * 128, h, N_NODES, l > 0 ? 1 : 0);
    }
    hipMemsetAsync(pool, 0, ((size_t)NGRAPH * 128 + NGRAPH) * 4, stream);
    k_pool<<<1024, 256, 0, stream>>>(h, gn + 3 * 128, bn + 3 * 128, bat, pool, cnt, N_NODES);
    k_read<<<NGRAPH, 64, 0, stream>>>(pool, cnt, Wp, bp, out);
}

// Round 3
// 4731.112 us; speedup vs baseline: 1.1769x; 1.1769x over previous
//
#include <hip/hip_runtime.h>

#define N_NODES 100000
#define N_EDGES 600000
#define NGRAPH 512
#define NOPS_T 8
#define EPS_MSG 1e-7f
#define EPS_LN 1e-5f

typedef unsigned short u16;
typedef unsigned int u32;
typedef __attribute__((ext_vector_type(8))) short short8;   // 8 bf16 (4 VGPRs) MFMA A/B frag
typedef __attribute__((ext_vector_type(4))) float f32x4;    // MFMA C/D frag

__device__ __forceinline__ float bf2f(u16 u) {
    union { float f; u32 i; } v; v.i = ((u32)u) << 16; return v.f;
}
__device__ __forceinline__ u16 f2bf(float f) {
    union { float f; u32 i; } v; v.f = f;
    u32 r = (v.i + 0x7fffu + ((v.i >> 16) & 1u)) >> 16;   // RNE
    return (u16)r;
}
__device__ __forceinline__ float wave_sum(float v) {
    #pragma unroll
    for (int off = 32; off > 0; off >>= 1) v += __shfl_xor(v, off, 64);
    return v;
}

// =============== encoder: h2 = bf16(x @ We + be); agg = 0 ===============
// MFMA 16x16x32, M=16/wave, N=128 (8 n-tiles), K=128 (4 k-steps).
__global__ __launch_bounds__(256, 1) void k_enc(const float* __restrict__ x,
                                                const float* __restrict__ We,
                                                const float* __restrict__ be,
                                                u16* __restrict__ h2,
                                                float* __restrict__ agg) {
    __shared__ __align__(16) u16 sWe[128 * 136];   // We^T padded (+8): row n, k contiguous
    __shared__ float sB[128];
    int tid = threadIdx.x;
    for (int i = tid; i < 128 * 128; i += 256) { int k = i >> 7, n = i & 127; sWe[n * 136 + k] = f2bf(We[i]); }
    if (tid < 128) sB[tid] = be[tid];
    __syncthreads();
    int wave = tid >> 6, lane = tid & 63, q = lane >> 4, c = lane & 15;
    for (int tile = blockIdx.x * 4 + wave; tile < N_NODES / 16; tile += gridDim.x * 4) {
        int n0 = tile * 16;
        const float4* xp = (const float4*)(x + (size_t)(n0 + c) * 128);
        short8 af[4];
        #pragma unroll
        for (int ks = 0; ks < 4; ks++) {
            float4 v0 = xp[ks * 8 + q * 2], v1 = xp[ks * 8 + q * 2 + 1];
            short8 a;
            a[0] = (short)f2bf(v0.x); a[1] = (short)f2bf(v0.y);
            a[2] = (short)f2bf(v0.z); a[3] = (short)f2bf(v0.w);
            a[4] = (short)f2bf(v1.x); a[5] = (short)f2bf(v1.y);
            a[6] = (short)f2bf(v1.z); a[7] = (short)f2bf(v1.w);
            af[ks] = a;
        }
        f32x4 acc[8];
        #pragma unroll
        for (int t = 0; t < 8; t++) {
            f32x4 a4 = {0.f, 0.f, 0.f, 0.f};
            const short8* bp = (const short8*)(sWe + (t * 16 + c) * 136);
            #pragma unroll
            for (int ks = 0; ks < 4; ks++)
                a4 = __builtin_amdgcn_mfma_f32_16x16x32_bf16(af[ks], bp[ks * 4 + q], a4, 0, 0, 0);
            acc[t] = a4;
        }
        u16* h2b = h2 + (size_t)n0 * 128;
        float* agb = agg + (size_t)n0 * 128;
        #pragma unroll
        for (int t = 0; t < 8; t++)
            #pragma unroll
            for (int i = 0; i < 4; i++) {
                int idx = (q * 4 + i) * 128 + t * 16 + c;     // D: row=q*4+i, col=t*16+c
                h2b[idx] = f2bf(acc[t][i] + sB[t * 16 + c]);
                agb[idx] = 0.f;
            }
    }
}

// =============== edges: agg[dst] += relu(h2[src] + Etab[attr]) + eps ===============
// 8 edges/block, 32 lanes/edge, 4 dims/lane (8B bf16 loads, 4 fp32 atomics).
__global__ __launch_bounds__(256) void k_edge(const int* __restrict__ ei,
                                              const int* __restrict__ ea,
                                              const float* __restrict__ Et,
                                              const u16* __restrict__ h2,
                                              float* __restrict__ agg) {
    __shared__ float4 sE[NOPS_T * 32];
    int tid = threadIdx.x;
    sE[tid] = ((const float4*)Et)[tid];
    __syncthreads();
    int e = blockIdx.x * 8 + (tid >> 5);
    int g = tid & 31;
    int s = ei[e], d = ei[N_EDGES + e], a = ea[e];
    uint2 hv = *(const uint2*)(h2 + (size_t)s * 128 + g * 4);
    float4 ev = sE[a * 32 + g];
    float m0 = fmaxf(bf2f((u16)(hv.x & 0xffff)) + ev.x, 0.f) + EPS_MSG;
    float m1 = fmaxf(bf2f((u16)(hv.x >> 16))    + ev.y, 0.f) + EPS_MSG;
    float m2 = fmaxf(bf2f((u16)(hv.y & 0xffff)) + ev.z, 0.f) + EPS_MSG;
    float m3 = fmaxf(bf2f((u16)(hv.y >> 16))    + ev.w, 0.f) + EPS_MSG;
    float* ap = agg + (size_t)d * 128 + g * 4;
    unsafeAtomicAdd(ap + 0, m0);
    unsafeAtomicAdd(ap + 1, m1);
    unsafeAtomicAdd(ap + 2, m2);
    unsafeAtomicAdd(ap + 3, m3);
}

// =============== fused layer: full GENConv MLP + LN epilogues ===============
// Per wave, per 16-node tile:
//   x = bf16(h2 + agg)                         (A-frags from global)
//   GEMM1: y_pre = x @ W1  (N=256: 16 n-tiles × 4 k-steps MFMA)
//   +b1, LN(256) in-register (quad shfl_xor), ReLU
//   y -> wave-private LDS (bf16, 64-col chunks) -> A-frags
//   GEMM2: o = y @ W2 (+b2, +h resid)
//   mode0: h=o; h2_next=bf16(relu(LN(o))); agg=0
//   mode1 (last layer): final LN -> atomic pool/cnt
// LDS: W1^T 69632 + W2^T 67584 + yst 9216 + params 4608 = 151040 B -> 1 block/CU.
__global__ __launch_bounds__(256, 1) void k_fused(
    const u16* __restrict__ h2_in, float* __restrict__ agg, float* __restrict__ h,
    const float* __restrict__ W1, const float* __restrict__ b1,
    const float* __restrict__ g1, const float* __restrict__ bb1,
    const float* __restrict__ W2, const float* __restrict__ b2,
    const float* __restrict__ gno, const float* __restrict__ bno,
    u16* __restrict__ h2_out, const int* __restrict__ batch,
    float* __restrict__ pool, float* __restrict__ cnt,
    int resid, int do_pool) {
    __shared__ __align__(16) u16 sW1[256 * 136];   // W1^T: [n=0..255][k=0..127], +8 pad
    __shared__ __align__(16) u16 sW2[128 * 264];   // W2^T: [n=0..127][k=0..255], +8 pad
    __shared__ __align__(16) u16 sY[4][16 * 72];   // per-wave y staging, 16 rows × 64(+8) cols
    __shared__ float sP[1152];                     // b1|g1|bb1 (256 each), b2|gno|bno (128 each)
    int tid = threadIdx.x;
    for (int i = tid; i < 128 * 256; i += 256) { int k = i >> 8, n = i & 255; sW1[n * 136 + k] = f2bf(W1[i]); }
    for (int i = tid; i < 256 * 128; i += 256) { int k = i >> 7, n = i & 127; sW2[n * 264 + k] = f2bf(W2[i]); }
    sP[tid] = b1[tid]; sP[256 + tid] = g1[tid]; sP[512 + tid] = bb1[tid];
    if (tid < 128) { sP[768 + tid] = b2[tid]; sP[896 + tid] = gno[tid]; sP[1024 + tid] = bno[tid]; }
    __syncthreads();

    int wave = tid >> 6, lane = tid & 63, q = lane >> 4, c = lane & 15;
    u16* yst = sY[wave];
    for (int tile = blockIdx.x * 4 + wave; tile < N_NODES / 16; tile += gridDim.x * 4) {
        int n0 = tile * 16;
        // ---- A fragments: x = h2 + agg, rounded to bf16 ----
        const short8* h2p = (const short8*)(h2_in + (size_t)(n0 + c) * 128);
        const float4* agp = (const float4*)(agg + (size_t)(n0 + c) * 128);
        short8 af[4];
        #pragma unroll
        for (int ks = 0; ks < 4; ks++) {
            short8 hv = h2p[ks * 4 + q];
            float4 u0 = agp[ks * 8 + q * 2], u1 = agp[ks * 8 + q * 2 + 1];
            short8 a;
            a[0] = (short)f2bf(bf2f((u16)hv[0]) + u0.x);
            a[1] = (short)f2bf(bf2f((u16)hv[1]) + u0.y);
            a[2] = (short)f2bf(bf2f((u16)hv[2]) + u0.z);
            a[3] = (short)f2bf(bf2f((u16)hv[3]) + u0.w);
            a[4] = (short)f2bf(bf2f((u16)hv[4]) + u1.x);
            a[5] = (short)f2bf(bf2f((u16)hv[5]) + u1.y);
            a[6] = (short)f2bf(bf2f((u16)hv[6]) + u1.z);
            a[7] = (short)f2bf(bf2f((u16)hv[7]) + u1.w);
            af[ks] = a;
        }
        // ---- residual prefetch (D-layout addresses) ----
        float rr[8][4];
        float* hb = h + (size_t)n0 * 128;
        if (resid) {
            #pragma unroll
            for (int t2 = 0; t2 < 8; t2++)
                #pragma unroll
                for (int i = 0; i < 4; i++) rr[t2][i] = hb[(q * 4 + i) * 128 + t2 * 16 + c];
        }
        // ---- GEMM1 ----
        f32x4 acc[16];
        #pragma unroll
        for (int t = 0; t < 16; t++) {
            f32x4 a4 = {0.f, 0.f, 0.f, 0.f};
            const short8* bp = (const short8*)(sW1 + (t * 16 + c) * 136);
            #pragma unroll
            for (int ks = 0; ks < 4; ks++)
                a4 = __builtin_amdgcn_mfma_f32_16x16x32_bf16(af[ks], bp[ks * 4 + q], a4, 0, 0, 0);
            acc[t] = a4;
        }
        // ---- +b1, LN over 256, ReLU (in-register; rows live in one quad) ----
        float sm[4] = {0, 0, 0, 0}, sq[4] = {0, 0, 0, 0};
        #pragma unroll
        for (int t = 0; t < 16; t++)
            #pragma unroll
            for (int i = 0; i < 4; i++) {
                float v = acc[t][i] + sP[t * 16 + c];
                acc[t][i] = v; sm[i] += v; sq[i] += v * v;
            }
        #pragma unroll
        for (int i = 0; i < 4; i++)
            #pragma unroll
            for (int m = 1; m < 16; m <<= 1) { sm[i] += __shfl_xor(sm[i], m, 64); sq[i] += __shfl_xor(sq[i], m, 64); }
        float mean[4], rs[4];
        #pragma unroll
        for (int i = 0; i < 4; i++) {
            mean[i] = sm[i] * (1.f / 256.f);
            float var = fmaxf(sq[i] * (1.f / 256.f) - mean[i] * mean[i], 0.f);
            rs[i] = rsqrtf(var + EPS_LN);
        }
        #pragma unroll
        for (int t = 0; t < 16; t++)
            #pragma unroll
            for (int i = 0; i < 4; i++) {
                int n = t * 16 + c;
                acc[t][i] = fmaxf(sP[256 + n] * (acc[t][i] - mean[i]) * rs[i] + sP[512 + n], 0.f);
            }
        // ---- GEMM2 via 4 chunks of K=64 (wave-private LDS transpose, no barriers) ----
        f32x4 acc2[8];
        #pragma unroll
        for (int t2 = 0; t2 < 8; t2++) acc2[t2] = (f32x4){0.f, 0.f, 0.f, 0.f};
        #pragma unroll
        for (int ch = 0; ch < 4; ch++) {
            #pragma unroll
            for (int tt = 0; tt < 4; tt++) {
                int t = ch * 4 + tt;
                #pragma unroll
                for (int i = 0; i < 4; i++) yst[(q * 4 + i) * 72 + tt * 16 + c] = f2bf(acc[t][i]);
            }
            #pragma unroll
            for (int ksl = 0; ksl < 2; ksl++) {
                short8 a2 = *(const short8*)(yst + c * 72 + ksl * 32 + q * 8);
                #pragma unroll
                for (int t2 = 0; t2 < 8; t2++) {
                    const short8* bp2 = (const short8*)(sW2 + (t2 * 16 + c) * 264 + ch * 64 + ksl * 32);
                    acc2[t2] = __builtin_amdgcn_mfma_f32_16x16x32_bf16(a2, bp2[q], acc2[t2], 0, 0, 0);
                }
            }
        }
        // ---- epilogue: +b2 (+resid), then LN over 128 ----
        float* agb = agg + (size_t)n0 * 128;
        float sm2[4] = {0, 0, 0, 0}, sq2[4] = {0, 0, 0, 0};
        float vout[8][4];
        #pragma unroll
        for (int t2 = 0; t2 < 8; t2++)
            #pragma unroll
            for (int i = 0; i < 4; i++) {
                float v = acc2[t2][i] + sP[768 + t2 * 16 + c];
                if (resid) v += rr[t2][i];
                vout[t2][i] = v; sm2[i] += v; sq2[i] += v * v;
            }
        #pragma unroll
        for (int i = 0; i < 4; i++)
            #pragma unroll
            for (int m = 1; m < 16; m <<= 1) { sm2[i] += __shfl_xor(sm2[i], m, 64); sq2[i] += __shfl_xor(sq2[i], m, 64); }
        float mean2[4], rs2[4];
        #pragma unroll
        for (int i = 0; i < 4; i++) {
            mean2[i] = sm2[i] * (1.f / 128.f);
            float var = fmaxf(sq2[i] * (1.f / 128.f) - mean2[i] * mean2[i], 0.f);
            rs2[i] = rsqrtf(var + EPS_LN);
        }
        if (!do_pool) {
            u16* h2b = h2_out + (size_t)n0 * 128;
            #pragma unroll
            for (int t2 = 0; t2 < 8; t2++)
                #pragma unroll
                for (int i = 0; i < 4; i++) {
                    int col = t2 * 16 + c, idx = (q * 4 + i) * 128 + col;
                    float v = vout[t2][i];
                    hb[idx] = v;                                  // residual for next layer
                    float o = sP[896 + col] * (v - mean2[i]) * rs2[i] + sP[1024 + col];
                    h2b[idx] = f2bf(fmaxf(o, 0.f));               // next conv input
                    agb[idx] = 0.f;                               // reset for next edge pass
                }
        } else {
            int bg[4];
            #pragma unroll
            for (int i = 0; i < 4; i++) bg[i] = batch[n0 + q * 4 + i];
            #pragma unroll
            for (int t2 = 0; t2 < 8; t2++)
                #pragma unroll
                for (int i = 0; i < 4; i++) {
                    int col = t2 * 16 + c;
                    float o = sP[896 + col] * (vout[t2][i] - mean2[i]) * rs2[i] + sP[1024 + col];
                    unsafeAtomicAdd(&pool[(size_t)bg[i] * 128 + col], o);
                }
            if (c == 0)
                #pragma unroll
                for (int i = 0; i < 4; i++) unsafeAtomicAdd(&cnt[bg[i]], 1.f);
        }
    }
}

// =============== readout: sigmoid(mean_pool @ Wp + bp) ===============
__global__ __launch_bounds__(64) void k_read(const float* __restrict__ pool,
                                             const float* __restrict__ cnt,
                                             const float* __restrict__ Wp,
                                             const float* __restrict__ bp,
                                             float* __restrict__ out) {
    int g = blockIdx.x, lane = threadIdx.x;
    float inv = 1.f / fmaxf(cnt[g], 1.f);
    float d = (pool[(size_t)g * 128 + lane] * Wp[lane] +
               pool[(size_t)g * 128 + 64 + lane] * Wp[64 + lane]) * inv;
    float s = wave_sum(d);
    if (lane == 0) out[g] = 1.f / (1.f + expf(-(s + bp[0])));
}

extern "C" void kernel_launch(void* const* d_in, const int* in_sizes, int n_in,
                              void* d_out, int out_size, void* d_ws, size_t ws_size,
                              hipStream_t stream) {
    const float* x   = (const float*)d_in[0];
    const int*   ei  = (const int*)d_in[1];
    const int*   ea  = (const int*)d_in[2];
    const int*   bat = (const int*)d_in[3];
    const float* We  = (const float*)d_in[4];
    const float* be  = (const float*)d_in[5];
    const float* Et  = (const float*)d_in[6];
    const float* W1  = (const float*)d_in[7];
    const float* b1  = (const float*)d_in[8];
    const float* g1  = (const float*)d_in[9];
    const float* bb1 = (const float*)d_in[10];
    const float* W2  = (const float*)d_in[11];
    const float* b2  = (const float*)d_in[12];
    const float* gn  = (const float*)d_in[13];
    const float* bn  = (const float*)d_in[14];
    const float* Wp  = (const float*)d_in[15];
    const float* bp  = (const float*)d_in[16];
    float* out = (float*)d_out;

    char* w = (char*)d_ws;
    float* h    = (float*)w;  w += (size_t)N_NODES * 128 * 4;
    float* agg  = (float*)w;  w += (size_t)N_NODES * 128 * 4;
    u16*   h2   = (u16*)w;    w += (size_t)N_NODES * 128 * 2;
    float* pool = (float*)w;  w += (size_t)NGRAPH * 128 * 4;
    float* cnt  = (float*)w;  w += (size_t)NGRAPH * 4;

    hipMemsetAsync(pool, 0, ((size_t)NGRAPH * 128 + NGRAPH) * 4, stream);
    k_enc<<<256, 256, 0, stream>>>(x, We, be, h2, agg);
    for (int l = 0; l < 4; l++) {
        k_edge<<<N_EDGES / 8, 256, 0, stream>>>(ei, ea, Et, h2, agg);
        k_fused<<<256, 256, 0, stream>>>(h2, agg, h,
                                         W1 + (size_t)l * 32768, b1 + l * 256,
                                         g1 + l * 256, bb1 + l * 256,
                                         W2 + (size_t)l * 32768, b2 + l * 128,
                                         gn + l * 128, bn + l * 128,
                                         h2, bat, pool, cnt,
                                         l > 0 ? 1 : 0, l == 3 ? 1 : 0);
    }
    k_read<<<NGRAPH, 64, 0, stream>>>(pool, cnt, Wp, bp, out);
}

// Round 4
// 838.263 us; speedup vs baseline: 6.6426x; 5.6439x over previous
//
#include <hip/hip_runtime.h>

#define N_NODES 100000
#define N_EDGES 600000
#define NGRAPH 512
#define NOPS_T 8
#define EPS_MSG 1e-7f
#define EPS_LN 1e-5f

typedef unsigned short u16;
typedef unsigned int u32;
typedef __attribute__((ext_vector_type(8))) short short8;   // 8 bf16 (4 VGPRs) MFMA A/B frag
typedef __attribute__((ext_vector_type(4))) float f32x4;    // MFMA C/D frag

__device__ __forceinline__ float bf2f(u16 u) {
    union { float f; u32 i; } v; v.i = ((u32)u) << 16; return v.f;
}
__device__ __forceinline__ u16 f2bf(float f) {
    union { float f; u32 i; } v; v.f = f;
    u32 r = (v.i + 0x7fffu + ((v.i >> 16) & 1u)) >> 16;   // RNE
    return (u16)r;
}
__device__ __forceinline__ float wave_sum(float v) {
    #pragma unroll
    for (int off = 32; off > 0; off >>= 1) v += __shfl_xor(v, off, 64);
    return v;
}

// =============== encoder: h2 = bf16(x @ We + be) ===============
__global__ __launch_bounds__(256, 1) void k_enc(const float* __restrict__ x,
                                                const float* __restrict__ We,
                                                const float* __restrict__ be,
                                                u16* __restrict__ h2) {
    __shared__ __align__(16) u16 sWe[128 * 136];   // We^T padded (+8): row n, k contiguous
    __shared__ float sB[128];
    int tid = threadIdx.x;
    for (int i = tid; i < 128 * 128; i += 256) { int k = i >> 7, n = i & 127; sWe[n * 136 + k] = f2bf(We[i]); }
    if (tid < 128) sB[tid] = be[tid];
    __syncthreads();
    int wave = tid >> 6, lane = tid & 63, q = lane >> 4, c = lane & 15;
    for (int tile = blockIdx.x * 4 + wave; tile < N_NODES / 16; tile += gridDim.x * 4) {
        int n0 = tile * 16;
        const float4* xp = (const float4*)(x + (size_t)(n0 + c) * 128);
        short8 af[4];
        #pragma unroll
        for (int ks = 0; ks < 4; ks++) {
            float4 v0 = xp[ks * 8 + q * 2], v1 = xp[ks * 8 + q * 2 + 1];
            short8 a;
            a[0] = (short)f2bf(v0.x); a[1] = (short)f2bf(v0.y);
            a[2] = (short)f2bf(v0.z); a[3] = (short)f2bf(v0.w);
            a[4] = (short)f2bf(v1.x); a[5] = (short)f2bf(v1.y);
            a[6] = (short)f2bf(v1.z); a[7] = (short)f2bf(v1.w);
            af[ks] = a;
        }
        f32x4 acc[8];
        #pragma unroll
        for (int t = 0; t < 8; t++) {
            f32x4 a4 = {0.f, 0.f, 0.f, 0.f};
            const short8* bp = (const short8*)(sWe + (t * 16 + c) * 136);
            #pragma unroll
            for (int ks = 0; ks < 4; ks++)
                a4 = __builtin_amdgcn_mfma_f32_16x16x32_bf16(af[ks], bp[ks * 4 + q], a4, 0, 0, 0);
            acc[t] = a4;
        }
        u16* h2b = h2 + (size_t)n0 * 128;
        #pragma unroll
        for (int t = 0; t < 8; t++)
            #pragma unroll
            for (int i = 0; i < 4; i++) {
                int idx = (q * 4 + i) * 128 + t * 16 + c;     // D: row=q*4+i, col=t*16+c
                h2b[idx] = f2bf(acc[t][i] + sB[t * 16 + c]);
            }
    }
}

// =============== CSR build (once per launch; edges static across layers) ===============
__global__ __launch_bounds__(256) void k_hist(const int* __restrict__ ei, int* __restrict__ deg) {
    int e = blockIdx.x * 256 + threadIdx.x;
    if (e < N_EDGES) atomicAdd(&deg[ei[N_EDGES + e]], 1);
}

// scan pass 1: per-block (1024 elems) exclusive scan + block sums
__global__ __launch_bounds__(256) void k_scan1(const int* __restrict__ deg,
                                               int* __restrict__ offs,
                                               int* __restrict__ bsum) {
    __shared__ int swv[4];
    int b = blockIdx.x, t = threadIdx.x;
    int base = b * 1024 + t * 4;
    int4 v = {0, 0, 0, 0};
    if (base < N_NODES) v = *(const int4*)(deg + base);   // N_NODES % 4 == 0
    int s = v.x + v.y + v.z + v.w;
    int lane = t & 63, wid = t >> 6;
    int incl = s;
    #pragma unroll
    for (int off = 1; off < 64; off <<= 1) {
        int o = __shfl_up(incl, off, 64);
        if (lane >= off) incl += o;
    }
    if (lane == 63) swv[wid] = incl;
    __syncthreads();
    int wbase = 0;
    #pragma unroll
    for (int w = 0; w < 4; w++) if (w < wid) wbase += swv[w];
    int ex = wbase + incl - s;
    if (base < N_NODES) {
        offs[base]     = ex;
        offs[base + 1] = ex + v.x;
        offs[base + 2] = ex + v.x + v.y;
        offs[base + 3] = ex + v.x + v.y + v.z;
    }
    if (t == 255) bsum[b] = wbase + incl;
}

// scan pass 2: single block scans block sums -> exclusive
__global__ __launch_bounds__(128) void k_scan2(int* __restrict__ bsum, int nb) {
    __shared__ int s[128];
    int t = threadIdx.x;
    int v = t < nb ? bsum[t] : 0;
    s[t] = v;
    __syncthreads();
    for (int off = 1; off < 128; off <<= 1) {
        int a = t >= off ? s[t - off] : 0;
        __syncthreads();
        s[t] += a;
        __syncthreads();
    }
    if (t < nb) bsum[t] = s[t] - v;
}

// scan pass 3: add block offsets; init cursor
__global__ __launch_bounds__(256) void k_scan3(int* __restrict__ offs,
                                               const int* __restrict__ bsum,
                                               int* __restrict__ cursor) {
    int b = blockIdx.x, t = threadIdx.x;
    int base = b * 1024 + t * 4;
    if (base >= N_NODES) return;
    int add = bsum[b];
    #pragma unroll
    for (int i = 0; i < 4; i++) {
        int o = offs[base + i] + add;
        offs[base + i] = o;
        cursor[base + i] = o;
    }
}

__global__ __launch_bounds__(256) void k_scatter(const int* __restrict__ ei,
                                                 const int* __restrict__ ea,
                                                 int* __restrict__ cursor,
                                                 int* __restrict__ csr) {
    int e = blockIdx.x * 256 + threadIdx.x;
    if (e >= N_EDGES) return;
    int s = ei[e], d = ei[N_EDGES + e], a = ea[e];
    int pos = atomicAdd(&cursor[d], 1);
    csr[pos] = s | (a << 24);                 // src < 2^17, attr < 8
}

// =============== aggregate (gather, no atomics): xin = bf16(h2 + sum msgs) ===============
// One half-wave (32 lanes) per dst node; 4 dims/lane.
__global__ __launch_bounds__(256) void k_agg(const int* __restrict__ offs,
                                             const int* __restrict__ deg,
                                             const int* __restrict__ csr,
                                             const float* __restrict__ Et,
                                             const u16* __restrict__ h2,
                                             u16* __restrict__ xin) {
    __shared__ float4 sE[NOPS_T * 32];
    int tid = threadIdx.x;
    sE[tid] = ((const float4*)Et)[tid];
    __syncthreads();
    int n = blockIdx.x * 8 + (tid >> 5);
    if (n >= N_NODES) return;
    int g = tid & 31;
    float a0 = 0.f, a1 = 0.f, a2 = 0.f, a3 = 0.f;
    int st = offs[n], dg = deg[n];
    for (int j = 0; j < dg; j++) {
        int p = csr[st + j];
        int s = p & 0xFFFFFF;
        int a = ((u32)p) >> 24;
        uint2 hv = *(const uint2*)(h2 + (size_t)s * 128 + g * 4);
        float4 ev = sE[a * 32 + g];
        a0 += fmaxf(bf2f((u16)(hv.x & 0xffff)) + ev.x, 0.f) + EPS_MSG;
        a1 += fmaxf(bf2f((u16)(hv.x >> 16))    + ev.y, 0.f) + EPS_MSG;
        a2 += fmaxf(bf2f((u16)(hv.y & 0xffff)) + ev.z, 0.f) + EPS_MSG;
        a3 += fmaxf(bf2f((u16)(hv.y >> 16))    + ev.w, 0.f) + EPS_MSG;
    }
    uint2 hd = *(const uint2*)(h2 + (size_t)n * 128 + g * 4);
    u32 o0 = (u32)f2bf(bf2f((u16)(hd.x & 0xffff)) + a0) |
             ((u32)f2bf(bf2f((u16)(hd.x >> 16))   + a1) << 16);
    u32 o1 = (u32)f2bf(bf2f((u16)(hd.y & 0xffff)) + a2) |
             ((u32)f2bf(bf2f((u16)(hd.y >> 16))   + a3) << 16);
    uint2 o = {o0, o1};
    *(uint2*)(xin + (size_t)n * 128 + g * 4) = o;
}

// =============== fused layer: GEMM1 + LN + ReLU + GEMM2 (+resid) + epilogue ===============
// 512 threads (8 waves, 2/SIMD), 1 block/CU (LDS 160.2 KB).
__global__ __launch_bounds__(512, 1) void k_fused(
    const u16* __restrict__ xin, float* __restrict__ h,
    const float* __restrict__ W1, const float* __restrict__ b1,
    const float* __restrict__ g1, const float* __restrict__ bb1,
    const float* __restrict__ W2, const float* __restrict__ b2,
    const float* __restrict__ gno, const float* __restrict__ bno,
    u16* __restrict__ h2_out, const int* __restrict__ batch,
    float* __restrict__ pool, float* __restrict__ cnt,
    int resid, int do_pool) {
    __shared__ __align__(16) u16 sW1[256 * 136];   // W1^T: [n][k], +8 pad      69632 B
    __shared__ __align__(16) u16 sW2[128 * 264];   // W2^T: [n][k], +8 pad      67584 B
    __shared__ __align__(16) u16 sY[8][16 * 72];   // per-wave y staging        18432 B
    __shared__ float sP[1152];                     // b1|g1|bb1|b2|gno|bno       4608 B
    int tid = threadIdx.x;
    for (int i = tid; i < 128 * 256; i += 512) { int k = i >> 8, n = i & 255; sW1[n * 136 + k] = f2bf(W1[i]); }
    for (int i = tid; i < 256 * 128; i += 512) { int k = i >> 7, n = i & 127; sW2[n * 264 + k] = f2bf(W2[i]); }
    if (tid < 256) { sP[tid] = b1[tid]; sP[256 + tid] = g1[tid]; sP[512 + tid] = bb1[tid]; }
    if (tid < 128) { sP[768 + tid] = b2[tid]; sP[896 + tid] = gno[tid]; sP[1024 + tid] = bno[tid]; }
    __syncthreads();

    int wave = tid >> 6, lane = tid & 63, q = lane >> 4, c = lane & 15;
    u16* yst = sY[wave];
    for (int tile = blockIdx.x * 8 + wave; tile < N_NODES / 16; tile += gridDim.x * 8) {
        int n0 = tile * 16;
        // ---- A fragments straight from xin (bf16) ----
        const short8* xp = (const short8*)(xin + (size_t)(n0 + c) * 128);
        short8 af[4];
        #pragma unroll
        for (int ks = 0; ks < 4; ks++) af[ks] = xp[ks * 4 + q];
        // ---- residual prefetch (D-layout addresses) ----
        float rr[8][4];
        float* hb = h + (size_t)n0 * 128;
        if (resid) {
            #pragma unroll
            for (int t2 = 0; t2 < 8; t2++)
                #pragma unroll
                for (int i = 0; i < 4; i++) rr[t2][i] = hb[(q * 4 + i) * 128 + t2 * 16 + c];
        }
        // ---- GEMM1 ----
        f32x4 acc[16];
        #pragma unroll
        for (int t = 0; t < 16; t++) {
            f32x4 a4 = {0.f, 0.f, 0.f, 0.f};
            const short8* bp = (const short8*)(sW1 + (t * 16 + c) * 136);
            #pragma unroll
            for (int ks = 0; ks < 4; ks++)
                a4 = __builtin_amdgcn_mfma_f32_16x16x32_bf16(af[ks], bp[ks * 4 + q], a4, 0, 0, 0);
            acc[t] = a4;
        }
        // ---- +b1, LN over 256, ReLU (in-register; rows live in one quad) ----
        float sm[4] = {0, 0, 0, 0}, sq[4] = {0, 0, 0, 0};
        #pragma unroll
        for (int t = 0; t < 16; t++)
            #pragma unroll
            for (int i = 0; i < 4; i++) {
                float v = acc[t][i] + sP[t * 16 + c];
                acc[t][i] = v; sm[i] += v; sq[i] += v * v;
            }
        #pragma unroll
        for (int i = 0; i < 4; i++)
            #pragma unroll
            for (int m = 1; m < 16; m <<= 1) { sm[i] += __shfl_xor(sm[i], m, 64); sq[i] += __shfl_xor(sq[i], m, 64); }
        float mean[4], rs[4];
        #pragma unroll
        for (int i = 0; i < 4; i++) {
            mean[i] = sm[i] * (1.f / 256.f);
            float var = fmaxf(sq[i] * (1.f / 256.f) - mean[i] * mean[i], 0.f);
            rs[i] = rsqrtf(var + EPS_LN);
        }
        #pragma unroll
        for (int t = 0; t < 16; t++)
            #pragma unroll
            for (int i = 0; i < 4; i++) {
                int n = t * 16 + c;
                acc[t][i] = fmaxf(sP[256 + n] * (acc[t][i] - mean[i]) * rs[i] + sP[512 + n], 0.f);
            }
        // ---- GEMM2 via 4 chunks of K=64 (wave-private LDS transpose, no barriers) ----
        f32x4 acc2[8];
        #pragma unroll
        for (int t2 = 0; t2 < 8; t2++) acc2[t2] = (f32x4){0.f, 0.f, 0.f, 0.f};
        #pragma unroll
        for (int ch = 0; ch < 4; ch++) {
            #pragma unroll
            for (int tt = 0; tt < 4; tt++) {
                int t = ch * 4 + tt;
                #pragma unroll
                for (int i = 0; i < 4; i++) yst[(q * 4 + i) * 72 + tt * 16 + c] = f2bf(acc[t][i]);
            }
            #pragma unroll
            for (int ksl = 0; ksl < 2; ksl++) {
                short8 a2 = *(const short8*)(yst + c * 72 + ksl * 32 + q * 8);
                #pragma unroll
                for (int t2 = 0; t2 < 8; t2++) {
                    const short8* bp2 = (const short8*)(sW2 + (t2 * 16 + c) * 264 + ch * 64 + ksl * 32);
                    acc2[t2] = __builtin_amdgcn_mfma_f32_16x16x32_bf16(a2, bp2[q], acc2[t2], 0, 0, 0);
                }
            }
        }
        // ---- epilogue: +b2 (+resid), then LN over 128 ----
        float sm2[4] = {0, 0, 0, 0}, sq2[4] = {0, 0, 0, 0};
        float vout[8][4];
        #pragma unroll
        for (int t2 = 0; t2 < 8; t2++)
            #pragma unroll
            for (int i = 0; i < 4; i++) {
                float v = acc2[t2][i] + sP[768 + t2 * 16 + c];
                if (resid) v += rr[t2][i];
                vout[t2][i] = v; sm2[i] += v; sq2[i] += v * v;
            }
        #pragma unroll
        for (int i = 0; i < 4; i++)
            #pragma unroll
            for (int m = 1; m < 16; m <<= 1) { sm2[i] += __shfl_xor(sm2[i], m, 64); sq2[i] += __shfl_xor(sq2[i], m, 64); }
        float mean2[4], rs2[4];
        #pragma unroll
        for (int i = 0; i < 4; i++) {
            mean2[i] = sm2[i] * (1.f / 128.f);
            float var = fmaxf(sq2[i] * (1.f / 128.f) - mean2[i] * mean2[i], 0.f);
            rs2[i] = rsqrtf(var + EPS_LN);
        }
        if (!do_pool) {
            u16* h2b = h2_out + (size_t)n0 * 128;
            #pragma unroll
            for (int t2 = 0; t2 < 8; t2++)
                #pragma unroll
                for (int i = 0; i < 4; i++) {
                    int col = t2 * 16 + c, idx = (q * 4 + i) * 128 + col;
                    float v = vout[t2][i];
                    hb[idx] = v;                                  // residual for next layer
                    float o = sP[896 + col] * (v - mean2[i]) * rs2[i] + sP[1024 + col];
                    h2b[idx] = f2bf(fmaxf(o, 0.f));               // next conv input
                }
        } else {
            int bg[4];
            #pragma unroll
            for (int i = 0; i < 4; i++) bg[i] = batch[n0 + q * 4 + i];
            #pragma unroll
            for (int t2 = 0; t2 < 8; t2++)
                #pragma unroll
                for (int i = 0; i < 4; i++) {
                    int col = t2 * 16 + c;
                    float o = sP[896 + col] * (vout[t2][i] - mean2[i]) * rs2[i] + sP[1024 + col];
                    unsafeAtomicAdd(&pool[(size_t)bg[i] * 128 + col], o);
                }
            if (c == 0)
                #pragma unroll
                for (int i = 0; i < 4; i++) unsafeAtomicAdd(&cnt[bg[i]], 1.f);
        }
    }
}

// =============== readout: sigmoid(mean_pool @ Wp + bp) ===============
__global__ __launch_bounds__(64) void k_read(const float* __restrict__ pool,
                                             const float* __restrict__ cnt,
                                             const float* __restrict__ Wp,
                                             const float* __restrict__ bp,
                                             float* __restrict__ out) {
    int g = blockIdx.x, lane = threadIdx.x;
    float inv = 1.f / fmaxf(cnt[g], 1.f);
    float d = (pool[(size_t)g * 128 + lane] * Wp[lane] +
               pool[(size_t)g * 128 + 64 + lane] * Wp[64 + lane]) * inv;
    float s = wave_sum(d);
    if (lane == 0) out[g] = 1.f / (1.f + expf(-(s + bp[0])));
}

extern "C" void kernel_launch(void* const* d_in, const int* in_sizes, int n_in,
                              void* d_out, int out_size, void* d_ws, size_t ws_size,
                              hipStream_t stream) {
    const float* x   = (const float*)d_in[0];
    const int*   ei  = (const int*)d_in[1];
    const int*   ea  = (const int*)d_in[2];
    const int*   bat = (const int*)d_in[3];
    const float* We  = (const float*)d_in[4];
    const float* be  = (const float*)d_in[5];
    const float* Et  = (const float*)d_in[6];
    const float* W1  = (const float*)d_in[7];
    const float* b1  = (const float*)d_in[8];
    const float* g1  = (const float*)d_in[9];
    const float* bb1 = (const float*)d_in[10];
    const float* W2  = (const float*)d_in[11];
    const float* b2  = (const float*)d_in[12];
    const float* gn  = (const float*)d_in[13];
    const float* bn  = (const float*)d_in[14];
    const float* Wp  = (const float*)d_in[15];
    const float* bp  = (const float*)d_in[16];
    float* out = (float*)d_out;

    char* w = (char*)d_ws;
    float* h    = (float*)w;  w += (size_t)N_NODES * 128 * 4;
    u16*   h2   = (u16*)w;    w += (size_t)N_NODES * 128 * 2;
    u16*   xin  = (u16*)w;    w += (size_t)N_NODES * 128 * 2;
    float* pool = (float*)w;  w += (size_t)NGRAPH * 128 * 4;
    float* cnt  = (float*)w;  w += (size_t)NGRAPH * 4;
    int*   deg  = (int*)w;    w += (size_t)N_NODES * 4;
    int*   offs = (int*)w;    w += (size_t)N_NODES * 4;
    int*   curs = (int*)w;    w += (size_t)N_NODES * 4;
    int*   bsum = (int*)w;    w += 128 * 4;
    int*   csr  = (int*)w;    w += (size_t)N_EDGES * 4;

    const int NB_SCAN = (N_NODES + 1023) / 1024;   // 98

    hipMemsetAsync(pool, 0, ((size_t)NGRAPH * 128 + NGRAPH) * 4, stream);
    hipMemsetAsync(deg, 0, (size_t)N_NODES * 4, stream);
    // CSR build (edges are static across layers — build once per launch)
    k_hist<<<(N_EDGES + 255) / 256, 256, 0, stream>>>(ei, deg);
    k_scan1<<<NB_SCAN, 256, 0, stream>>>(deg, offs, bsum);
    k_scan2<<<1, 128, 0, stream>>>(bsum, NB_SCAN);
    k_scan3<<<NB_SCAN, 256, 0, stream>>>(offs, bsum, curs);
    k_scatter<<<(N_EDGES + 255) / 256, 256, 0, stream>>>(ei, ea, curs, csr);

    k_enc<<<256, 256, 0, stream>>>(x, We, be, h2);
    for (int l = 0; l < 4; l++) {
        k_agg<<<(N_NODES + 7) / 8, 256, 0, stream>>>(offs, deg, csr, Et, h2, xin);
        k_fused<<<256, 512, 0, stream>>>(xin, h,
                                         W1 + (size_t)l * 32768, b1 + l * 256,
                                         g1 + l * 256, bb1 + l * 256,
                                         W2 + (size_t)l * 32768, b2 + l * 128,
                                         gn + l * 128, bn + l * 128,
                                         h2, bat, pool, cnt,
                                         l > 0 ? 1 : 0, l == 3 ? 1 : 0);
    }
    k_read<<<NGRAPH, 64, 0, stream>>>(pool, cnt, Wp, bp, out);
}